// Round 1
// baseline (375.730 us; speedup 1.0000x reference)
//
#include <hip/hip_runtime.h>

// ---------------- problem constants ----------------
#define DIMX  4096
#define NH    32
#define HD    128
#define BB    2
#define TT    1024
#define MROWS (BB*TT)          // 2048
#define CQKV  3072             // compact qkv cols: 1024 q_red | 1024 k | 1024 v
// (1/sqrt(128)) * log2(e): lets attention use exp2 directly
#define SCALE_Q 0.12751743f

typedef _Float16 half_t;
typedef __attribute__((ext_vector_type(4))) _Float16 f16x4;
typedef __attribute__((ext_vector_type(8))) _Float16 f16x8;
typedef __attribute__((ext_vector_type(4))) float    f32x4;

// async global->LDS, 16B/lane; LDS dest = wave-uniform base + lane*16
__device__ __forceinline__ void async_copy16(const void* gsrc, void* ldst) {
  __builtin_amdgcn_global_load_lds(
      (const __attribute__((address_space(1))) unsigned int*)gsrc,
      (__attribute__((address_space(3))) unsigned int*)ldst,
      16, 0, 0);
}

// ---------------- fp32 -> fp16 conversion ----------------
__global__ __launch_bounds__(256) void cvt_f32_f16_kernel(
    const float4* __restrict__ src, f16x4* __restrict__ dst, int n4) {
  int stride = gridDim.x * blockDim.x;
  for (int i = blockIdx.x * blockDim.x + threadIdx.x; i < n4; i += stride) {
    float4 f = src[i];
    f16x4 h;
    h.x = (_Float16)f.x; h.y = (_Float16)f.y;
    h.z = (_Float16)f.z; h.w = (_Float16)f.w;
    dst[i] = h;
  }
}

// ---------------- fold W1 -> W1f [3072][4096] fp16, b1f [3072] f32 ----------
// rows 0..1023:  q_red rows = (sum of 4 q rows) * SCALE_Q
// rows 1024..3071: k/v rows copied (W1 row = row + 3072)
__global__ __launch_bounds__(256) void fold_w1_kernel(
    const float* __restrict__ W1, const float* __restrict__ b1,
    half_t* __restrict__ W1f, float* __restrict__ b1f)
{
  long idx = (long)blockIdx.x * 256 + threadIdx.x;   // 3072*1024
  int row = (int)(idx >> 10);
  int c4  = ((int)idx & 1023) << 2;
  f16x4 h;
  if (row < 1024) {
    const float* s = W1 + ((long)row << 2) * DIMX + c4;
    float4 a = *(const float4*)s;
    float4 b = *(const float4*)(s + DIMX);
    float4 c = *(const float4*)(s + 2 * DIMX);
    float4 d = *(const float4*)(s + 3 * DIMX);
    h.x = (_Float16)((a.x + b.x + c.x + d.x) * SCALE_Q);
    h.y = (_Float16)((a.y + b.y + c.y + d.y) * SCALE_Q);
    h.z = (_Float16)((a.z + b.z + c.z + d.z) * SCALE_Q);
    h.w = (_Float16)((a.w + b.w + c.w + d.w) * SCALE_Q);
    if (c4 == 0) {
      const float* bb = b1 + ((long)row << 2);
      b1f[row] = (bb[0] + bb[1] + bb[2] + bb[3]) * SCALE_Q;
    }
  } else {
    const float* s = W1 + ((long)(row + 3072)) * DIMX + c4;
    float4 a = *(const float4*)s;
    h.x = (_Float16)a.x; h.y = (_Float16)a.y;
    h.z = (_Float16)a.z; h.w = (_Float16)a.w;
    if (c4 == 0) b1f[row] = b1[row + 3072];
  }
  *(f16x4*)&W1f[(long)row * DIMX + c4] = h;
}

// ---------------- fold W2 -> W2f [4096][1024] fp16 ----------------
// W2f[n][j] = sum_{r<4} W2[n][4j+r]
__global__ __launch_bounds__(256) void fold_w2_kernel(
    const float* __restrict__ W2, half_t* __restrict__ W2f)
{
  long idx = (long)blockIdx.x * 256 + threadIdx.x;   // 4096*256
  int row = (int)(idx >> 8);
  int j4  = ((int)idx & 255) << 2;
  const float* s = W2 + (long)row * DIMX + ((long)j4 << 2);
  float4 a = *(const float4*)s;
  float4 b = *(const float4*)(s + 4);
  float4 c = *(const float4*)(s + 8);
  float4 d = *(const float4*)(s + 12);
  f16x4 h;
  h.x = (_Float16)(a.x + a.y + a.z + a.w);
  h.y = (_Float16)(b.x + b.y + b.z + b.w);
  h.z = (_Float16)(c.x + c.y + c.z + c.w);
  h.w = (_Float16)(d.x + d.y + d.z + d.w);
  *(f16x4*)&W2f[(long)row * 1024 + j4] = h;
}

// ---------------- NT GEMM: C[m,n] = sum_k A[m,k]*B[n,k] + bias[n] ----------
// m97 structure: tile 128x128, BK=32, 4 waves in 2x2; each wave 64x64 via
// 4x4 mfma_16x16x32 (16 MFMA vs 8 ds_read_b128 per K-step per wave).
// Staging: 16 KB/K-step = 4 async_copy16 per thread (width 16).
// 2-barrier schedule — T2 swizzle / vmcnt pipelining are NULL in this regime.
template<int OUT_IS_F16>
__global__ __launch_bounds__(256) void gemm_nt_bias(
    const half_t* __restrict__ A, const half_t* __restrict__ Bw,
    const float* __restrict__ bias, void* __restrict__ Cout,
    int M, int N, int K)
{
  __shared__ alignas(16) half_t As[128 * 32];   // 8 KB
  __shared__ alignas(16) half_t Bs[128 * 32];   // 8 KB

  const int tid  = threadIdx.x;
  const int lane = tid & 63;
  const int w    = tid >> 6;
  const long row0 = (long)blockIdx.y * 128;
  const long col0 = (long)blockIdx.x * 128;

  // staging: thread t -> row (t>>2) and row 64+(t>>2), col-slot (t&3)*8 halves
  // LDS addr = row*32 + (t&3)*8 halves = w*512 + lane*8  (linear in lane) ✓
  const int rr = tid >> 2;              // 0..63
  const int cc = (tid & 3) * 8;         // 0,8,16,24 (halves)
  const half_t* ga0 = A  + (row0 + rr)      * K + cc;
  const half_t* ga1 = A  + (row0 + 64 + rr) * K + cc;
  const half_t* gb0 = Bw + (col0 + rr)      * K + cc;
  const half_t* gb1 = Bw + (col0 + 64 + rr) * K + cc;
  half_t* la0 = &As[w * 512];
  half_t* la1 = &As[2048 + w * 512];
  half_t* lb0 = &Bs[w * 512];
  half_t* lb1 = &Bs[2048 + w * 512];

  // wave 2x2: wave w owns C[wm..wm+63][wn..wn+63]
  const int wm = (w >> 1) * 64;
  const int wn = (w & 1) * 64;
  const int fr = lane & 15;
  const int fk = (lane >> 4) * 8;
  const half_t* pa = &As[(wm + fr) * 32 + fk];
  const half_t* pb = &Bs[(wn + fr) * 32 + fk];

  f32x4 acc[4][4] = {};

  for (int kt = 0; kt < K; kt += 32) {
    __syncthreads();
    async_copy16(ga0 + kt, la0);
    async_copy16(ga1 + kt, la1);
    async_copy16(gb0 + kt, lb0);
    async_copy16(gb1 + kt, lb1);
    __syncthreads();   // compiler drains vmcnt(0) before s_barrier

    f16x8 af[4], bf[4];
#pragma unroll
    for (int mi = 0; mi < 4; ++mi) af[mi] = *(const f16x8*)(pa + mi * 16 * 32);
#pragma unroll
    for (int ni = 0; ni < 4; ++ni) bf[ni] = *(const f16x8*)(pb + ni * 16 * 32);
#pragma unroll
    for (int mi = 0; mi < 4; ++mi)
#pragma unroll
      for (int ni = 0; ni < 4; ++ni)
        acc[mi][ni] = __builtin_amdgcn_mfma_f32_16x16x32_f16(
            af[mi], bf[ni], acc[mi][ni], 0, 0, 0);
  }

  // C/D layout: col = lane&15, row = (lane>>4)*4 + r
  const int er = (lane >> 4) * 4;
  const int ec = lane & 15;
#pragma unroll
  for (int mi = 0; mi < 4; ++mi) {
#pragma unroll
    for (int ni = 0; ni < 4; ++ni) {
      long gn = col0 + wn + ni * 16 + ec;
      float bv = bias[gn];
#pragma unroll
      for (int r = 0; r < 4; ++r) {
        long gm = row0 + wm + mi * 16 + er + r;
        float v = acc[mi][ni][r] + bv;
        if (OUT_IS_F16) ((half_t*)Cout)[gm * N + gn] = (half_t)v;
        else            ((float*)Cout)[gm * N + gn]  = v;
      }
    }
  }
}

// ---------------- MFMA flash attention (compact 32-dim heads) --------------
// Block: 256 thr = 4 waves; wave w owns 16 queries [t0+16w, t0+16w+15].
// Two q-tiles per block {15-bx, bx} -> 17 chunks/block, perfectly balanced.
// Per 64-key chunk: S = Q.K^T (4 MFMA), P = exp2(S) masked -> LDS,
// O^T = Vt.P^T (6 MFMA; Vt row 32 = ones gives l in tile2 row 0).
#define VTS 72
#define PSS 72
__global__ __launch_bounds__(256, 4) void attn_kernel(
    const half_t* __restrict__ qkv,  // [MROWS][3072]
    half_t* __restrict__ attc)       // [MROWS][1024]
{
  __shared__ alignas(16) half_t Ks[64 * 32];        // [key][32]
  __shared__ alignas(16) half_t Vt[48 * VTS];       // [d][key], row 32 = ones
  __shared__ alignas(16) half_t Ps[4][16 * PSS];    // per-wave [q][key]

  const int tid  = threadIdx.x;
  const int lane = tid & 63;
  const int w    = tid >> 6;
  const int low  = lane & 15;
  const int quad = lane >> 4;
  const int bh   = blockIdx.y;
  const int b    = bh >> 5;
  const int h    = bh & 31;
  const long rb  = (long)b * TT;

  // ones row (d=32) of Vt, staged once (never overwritten)
  if (tid < 8) {
    f16x8 one;
#pragma unroll
    for (int i = 0; i < 8; ++i) one[i] = (_Float16)1.0f;
    *(f16x8*)&Vt[32 * VTS + tid * 8] = one;
  }

  const int srow = tid >> 2;            // 0..63
  const int sc4  = (tid & 3) << 3;      // 0,8,16,24
  half_t* ksdst  = &Ks[w * 512];        // wave-uniform; HW adds lane*16B
  half_t* psw    = &Ps[w][0];
  float*  Ob     = (float*)psw;         // epilogue overlay [q][36 floats]

  for (int pass = 0; pass < 2; ++pass) {
    const int tile = pass ? (int)blockIdx.x : 15 - (int)blockIdx.x;
    const int t0   = tile * 64;
    const int qg   = t0 + 16 * w;

    // Q fragment: A[m=low][k=quad*8+j]
    f16x8 qf = *(const f16x8*)&qkv[(rb + qg + low) * CQKV + h * 32 + quad * 8];

    f32x4 acc0 = {}, acc1 = {}, acc2 = {};
    const f32x4 zero = {};

    for (int c = 0; c <= t0; c += 64) {
      __syncthreads();
      // stage K (async direct-to-LDS) and V (register transpose scatter)
      const half_t* kg = &qkv[(rb + c + srow) * CQKV + 1024 + h * 32 + sc4];
      async_copy16(kg, ksdst);
      f16x8 vv = *(const f16x8*)(kg + 1024);
#pragma unroll
      for (int j = 0; j < 8; ++j)
        Vt[(sc4 + j) * VTS + srow] = vv[j];
      __syncthreads();

      // S = Q.K^T : C[m=q][n=key]
      f32x4 s[4];
#pragma unroll
      for (int st = 0; st < 4; ++st) {
        f16x8 kf = *(const f16x8*)&Ks[(st * 16 + low) * 32 + quad * 8];
        s[st] = __builtin_amdgcn_mfma_f32_16x16x32_f16(qf, kf, zero, 0, 0, 0);
      }

      // P = exp2(S) (causal mask only at diagonal chunk), write to LDS
      const bool diag = (c == t0);
#pragma unroll
      for (int st = 0; st < 4; ++st) {
#pragma unroll
        for (int r = 0; r < 4; ++r) {
          const int key = c + st * 16 + low;
          const int q   = qg + 4 * quad + r;
          float p = __builtin_amdgcn_exp2f(s[st][r]);
          if (diag && key > q) p = 0.f;
          psw[(4 * quad + r) * PSS + st * 16 + low] = (_Float16)p;
        }
      }

      // P frags (B: [n=q][k=key]) and Vt frags (A: [m=d][k=key])
      f16x8 p0 = *(const f16x8*)&psw[low * PSS + 0 * 32 + quad * 8];
      f16x8 p1 = *(const f16x8*)&psw[low * PSS + 1 * 32 + quad * 8];

      f16x8 v00 = *(const f16x8*)&Vt[(0  + low) * VTS + 0  + quad * 8];
      f16x8 v01 = *(const f16x8*)&Vt[(0  + low) * VTS + 32 + quad * 8];
      f16x8 v10 = *(const f16x8*)&Vt[(16 + low) * VTS + 0  + quad * 8];
      f16x8 v11 = *(const f16x8*)&Vt[(16 + low) * VTS + 32 + quad * 8];
      f16x8 v20 = *(const f16x8*)&Vt[(32 + low) * VTS + 0  + quad * 8];
      f16x8 v21 = *(const f16x8*)&Vt[(32 + low) * VTS + 32 + quad * 8];

      acc0 = __builtin_amdgcn_mfma_f32_16x16x32_f16(v00, p0, acc0, 0, 0, 0);
      acc0 = __builtin_amdgcn_mfma_f32_16x16x32_f16(v01, p1, acc0, 0, 0, 0);
      acc1 = __builtin_amdgcn_mfma_f32_16x16x32_f16(v10, p0, acc1, 0, 0, 0);
      acc1 = __builtin_amdgcn_mfma_f32_16x16x32_f16(v11, p1, acc1, 0, 0, 0);
      acc2 = __builtin_amdgcn_mfma_f32_16x16x32_f16(v20, p0, acc2, 0, 0, 0);
      acc2 = __builtin_amdgcn_mfma_f32_16x16x32_f16(v21, p1, acc2, 0, 0, 0);
    }

    // ---- epilogue ----
    __syncthreads();   // last chunk's Ps reads done before Ob overlay writes

    // l[q] lives in acc2[0] of lanes 0..15 (m=0 <=> d=32); broadcast by q
    float linv = 1.0f / __shfl(acc2[0], low);

    // O^T[d=16t+4quad+r][q=low] -> Ob[q][d], scaled
#pragma unroll
    for (int r = 0; r < 4; ++r) {
      Ob[low * 36 + 0  + 4 * quad + r] = acc0[r] * linv;
      Ob[low * 36 + 16 + 4 * quad + r] = acc1[r] * linv;
    }
    __syncthreads();

    // row-wise readback: lane (q=low, dblk=quad) -> 8 contiguous dims
    f16x8 ov;
#pragma unroll
    for (int i = 0; i < 8; ++i)
      ov[i] = (_Float16)Ob[low * 36 + quad * 8 + i];
    *(f16x8*)&attc[(rb + qg + low) * 1024 + h * 32 + quad * 8] = ov;
  }
}

// ---------------- launcher ----------------
extern "C" void kernel_launch(void* const* d_in, const int* in_sizes, int n_in,
                              void* d_out, int out_size, void* d_ws, size_t ws_size,
                              hipStream_t stream) {
  (void)in_sizes; (void)n_in; (void)out_size; (void)ws_size;
  const float* x  = (const float*)d_in[0];
  const float* W1 = (const float*)d_in[1];
  const float* b1 = (const float*)d_in[2];
  const float* W2 = (const float*)d_in[3];
  const float* b2 = (const float*)d_in[4];
  float* out = (float*)d_out;

  const size_t nX   = (size_t)MROWS * DIMX;   //  8,388,608
  const size_t nW1f = (size_t)CQKV  * DIMX;   // 12,582,912
  const size_t nW2f = (size_t)DIMX  * 1024;   //  4,194,304
  const size_t nQKV = (size_t)MROWS * CQKV;   //  6,291,456
  const size_t nATT = (size_t)MROWS * 1024;   //  2,097,152

  half_t* ws   = (half_t*)d_ws;
  half_t* xh   = ws;
  half_t* w1f  = xh   + nX;
  half_t* w2f  = w1f  + nW1f;
  half_t* qkvc = w2f  + nW2f;
  half_t* attc = qkvc + nQKV;
  float*  b1f  = (float*)(attc + nATT);       // 3072 floats

  cvt_f32_f16_kernel<<<4096, 256, 0, stream>>>((const float4*)x, (f16x4*)xh,
                                               (int)(nX / 4));
  fold_w1_kernel<<<12288, 256, 0, stream>>>(W1, b1, w1f, b1f);
  fold_w2_kernel<<<4096, 256, 0, stream>>>(W2, w2f);

  gemm_nt_bias<1><<<dim3(CQKV / 128, MROWS / 128), 256, 0, stream>>>(
      xh, w1f, b1f, (void*)qkvc, MROWS, CQKV, DIMX);

  attn_kernel<<<dim3(8, BB * NH), 256, 0, stream>>>(qkvc, attc);

  gemm_nt_bias<0><<<dim3(DIMX / 128, MROWS / 128), 256, 0, stream>>>(
      attc, w2f, b2, (void*)out, MROWS, DIMX, 1024);
}

// Round 2
// 367.848 us; speedup vs baseline: 1.0214x; 1.0214x over previous
//
#include <hip/hip_runtime.h>

// ---------------- problem constants ----------------
#define DIMX  4096
#define NH    32
#define HD    128
#define BB    2
#define TT    1024
#define MROWS (BB*TT)          // 2048
#define CQKV  3072             // compact qkv cols: 1024 q_red | 1024 k | 1024 v
// (1/sqrt(128)) * log2(e): lets attention use exp2 directly
#define SCALE_Q 0.12751743f

typedef _Float16 half_t;
typedef __attribute__((ext_vector_type(4))) _Float16 f16x4;
typedef __attribute__((ext_vector_type(8))) _Float16 f16x8;
typedef __attribute__((ext_vector_type(4))) float    f32x4;

// async global->LDS, 16B/lane; LDS dest = wave-uniform base + lane*16
__device__ __forceinline__ void async_copy16(const void* gsrc, void* ldst) {
  __builtin_amdgcn_global_load_lds(
      (const __attribute__((address_space(1))) unsigned int*)gsrc,
      (__attribute__((address_space(3))) unsigned int*)ldst,
      16, 0, 0);
}

// ---------------- fp32 -> fp16 conversion ----------------
__global__ __launch_bounds__(256) void cvt_f32_f16_kernel(
    const float4* __restrict__ src, f16x4* __restrict__ dst, int n4) {
  int stride = gridDim.x * blockDim.x;
  for (int i = blockIdx.x * blockDim.x + threadIdx.x; i < n4; i += stride) {
    float4 f = src[i];
    f16x4 h;
    h.x = (_Float16)f.x; h.y = (_Float16)f.y;
    h.z = (_Float16)f.z; h.w = (_Float16)f.w;
    dst[i] = h;
  }
}

// ---------------- fold W1 -> W1f [3072][4096] fp16, b1f [3072] f32 ----------
// rows 0..1023:  q_red rows = (sum of 4 q rows) * SCALE_Q
// rows 1024..3071: k/v rows copied (W1 row = row + 3072)
__global__ __launch_bounds__(256) void fold_w1_kernel(
    const float* __restrict__ W1, const float* __restrict__ b1,
    half_t* __restrict__ W1f, float* __restrict__ b1f)
{
  long idx = (long)blockIdx.x * 256 + threadIdx.x;   // 3072*1024
  int row = (int)(idx >> 10);
  int c4  = ((int)idx & 1023) << 2;
  f16x4 h;
  if (row < 1024) {
    const float* s = W1 + ((long)row << 2) * DIMX + c4;
    float4 a = *(const float4*)s;
    float4 b = *(const float4*)(s + DIMX);
    float4 c = *(const float4*)(s + 2 * DIMX);
    float4 d = *(const float4*)(s + 3 * DIMX);
    h.x = (_Float16)((a.x + b.x + c.x + d.x) * SCALE_Q);
    h.y = (_Float16)((a.y + b.y + c.y + d.y) * SCALE_Q);
    h.z = (_Float16)((a.z + b.z + c.z + d.z) * SCALE_Q);
    h.w = (_Float16)((a.w + b.w + c.w + d.w) * SCALE_Q);
    if (c4 == 0) {
      const float* bb = b1 + ((long)row << 2);
      b1f[row] = (bb[0] + bb[1] + bb[2] + bb[3]) * SCALE_Q;
    }
  } else {
    const float* s = W1 + ((long)(row + 3072)) * DIMX + c4;
    float4 a = *(const float4*)s;
    h.x = (_Float16)a.x; h.y = (_Float16)a.y;
    h.z = (_Float16)a.z; h.w = (_Float16)a.w;
    if (c4 == 0) b1f[row] = b1[row + 3072];
  }
  *(f16x4*)&W1f[(long)row * DIMX + c4] = h;
}

// ---------------- fold W2 -> W2f [4096][1024] fp16 ----------------
// W2f[n][j] = sum_{r<4} W2[n][4j+r]
__global__ __launch_bounds__(256) void fold_w2_kernel(
    const float* __restrict__ W2, half_t* __restrict__ W2f)
{
  long idx = (long)blockIdx.x * 256 + threadIdx.x;   // 4096*256
  int row = (int)(idx >> 8);
  int j4  = ((int)idx & 255) << 2;
  const float* s = W2 + (long)row * DIMX + ((long)j4 << 2);
  float4 a = *(const float4*)s;
  float4 b = *(const float4*)(s + 4);
  float4 c = *(const float4*)(s + 8);
  float4 d = *(const float4*)(s + 12);
  f16x4 h;
  h.x = (_Float16)(a.x + a.y + a.z + a.w);
  h.y = (_Float16)(b.x + b.y + b.z + b.w);
  h.z = (_Float16)(c.x + c.y + c.z + c.w);
  h.w = (_Float16)(d.x + d.y + d.z + d.w);
  *(f16x4*)&W2f[(long)row * 1024 + j4] = h;
}

// ---------------- NT GEMM: C[m,n] = sum_k A[m,k]*B[n,k] + bias[n] ----------
// m97 structure: tile 128x128, BK=32, 4 waves in 2x2; each wave 64x64 via
// 4x4 mfma_16x16x32 (16 MFMA vs 8 ds_read_b128 per K-step per wave).
// Used for GEMM2 only (grid 32x16 = 512 blocks = even 2/CU).
template<int OUT_IS_F16>
__global__ __launch_bounds__(256) void gemm_nt_bias(
    const half_t* __restrict__ A, const half_t* __restrict__ Bw,
    const float* __restrict__ bias, void* __restrict__ Cout,
    int M, int N, int K)
{
  __shared__ alignas(16) half_t As[128 * 32];   // 8 KB
  __shared__ alignas(16) half_t Bs[128 * 32];   // 8 KB

  const int tid  = threadIdx.x;
  const int lane = tid & 63;
  const int w    = tid >> 6;
  const long row0 = (long)blockIdx.y * 128;
  const long col0 = (long)blockIdx.x * 128;

  // staging: thread t -> row (t>>2) and row 64+(t>>2), col-slot (t&3)*8 halves
  // LDS addr = row*32 + (t&3)*8 halves = w*512 + lane*8  (linear in lane) ✓
  const int rr = tid >> 2;              // 0..63
  const int cc = (tid & 3) * 8;         // 0,8,16,24 (halves)
  const half_t* ga0 = A  + (row0 + rr)      * K + cc;
  const half_t* ga1 = A  + (row0 + 64 + rr) * K + cc;
  const half_t* gb0 = Bw + (col0 + rr)      * K + cc;
  const half_t* gb1 = Bw + (col0 + 64 + rr) * K + cc;
  half_t* la0 = &As[w * 512];
  half_t* la1 = &As[2048 + w * 512];
  half_t* lb0 = &Bs[w * 512];
  half_t* lb1 = &Bs[2048 + w * 512];

  // wave 2x2: wave w owns C[wm..wm+63][wn..wn+63]
  const int wm = (w >> 1) * 64;
  const int wn = (w & 1) * 64;
  const int fr = lane & 15;
  const int fk = (lane >> 4) * 8;
  const half_t* pa = &As[(wm + fr) * 32 + fk];
  const half_t* pb = &Bs[(wn + fr) * 32 + fk];

  f32x4 acc[4][4] = {};

  for (int kt = 0; kt < K; kt += 32) {
    __syncthreads();
    async_copy16(ga0 + kt, la0);
    async_copy16(ga1 + kt, la1);
    async_copy16(gb0 + kt, lb0);
    async_copy16(gb1 + kt, lb1);
    __syncthreads();   // compiler drains vmcnt(0) before s_barrier

    f16x8 af[4], bf[4];
#pragma unroll
    for (int mi = 0; mi < 4; ++mi) af[mi] = *(const f16x8*)(pa + mi * 16 * 32);
#pragma unroll
    for (int ni = 0; ni < 4; ++ni) bf[ni] = *(const f16x8*)(pb + ni * 16 * 32);
#pragma unroll
    for (int mi = 0; mi < 4; ++mi)
#pragma unroll
      for (int ni = 0; ni < 4; ++ni)
        acc[mi][ni] = __builtin_amdgcn_mfma_f32_16x16x32_f16(
            af[mi], bf[ni], acc[mi][ni], 0, 0, 0);
  }

  // C/D layout: col = lane&15, row = (lane>>4)*4 + r
  const int er = (lane >> 4) * 4;
  const int ec = lane & 15;
#pragma unroll
  for (int mi = 0; mi < 4; ++mi) {
#pragma unroll
    for (int ni = 0; ni < 4; ++ni) {
      long gn = col0 + wn + ni * 16 + ec;
      float bv = bias[gn];
#pragma unroll
      for (int r = 0; r < 4; ++r) {
        long gm = row0 + wm + mi * 16 + er + r;
        float v = acc[mi][ni][r] + bv;
        if (OUT_IS_F16) ((half_t*)Cout)[gm * N + gn] = (half_t)v;
        else            ((float*)Cout)[gm * N + gn]  = v;
      }
    }
  }
}

// ---------------- split-K NT GEMM (GEMM1): 2 K-slices, f32 partials --------
// Same 128x128/BK=32/16-MFMA-per-wave body; grid (N/128, M/128, 2) = 768
// blocks = exactly 3 blocks/CU (restores m114 barrier-drain overlap that the
// 384-block non-split version lost). Slice s computes K-range [s*K/2,(s+1)K/2)
// and writes raw f32 partials to Cp[s]; no bias here.
__global__ __launch_bounds__(256) void gemm_nt_splitk(
    const half_t* __restrict__ A, const half_t* __restrict__ Bw,
    float* __restrict__ Cp0, float* __restrict__ Cp1,
    int M, int N, int K)
{
  __shared__ alignas(16) half_t As[128 * 32];   // 8 KB
  __shared__ alignas(16) half_t Bs[128 * 32];   // 8 KB

  const int tid  = threadIdx.x;
  const int lane = tid & 63;
  const int w    = tid >> 6;
  const long row0 = (long)blockIdx.y * 128;
  const long col0 = (long)blockIdx.x * 128;
  const int  KH   = K >> 1;
  const long k0   = (long)blockIdx.z * KH;

  const int rr = tid >> 2;              // 0..63
  const int cc = (tid & 3) * 8;         // 0,8,16,24 (halves)
  const half_t* ga0 = A  + (row0 + rr)      * K + k0 + cc;
  const half_t* ga1 = A  + (row0 + 64 + rr) * K + k0 + cc;
  const half_t* gb0 = Bw + (col0 + rr)      * K + k0 + cc;
  const half_t* gb1 = Bw + (col0 + 64 + rr) * K + k0 + cc;
  half_t* la0 = &As[w * 512];
  half_t* la1 = &As[2048 + w * 512];
  half_t* lb0 = &Bs[w * 512];
  half_t* lb1 = &Bs[2048 + w * 512];

  const int wm = (w >> 1) * 64;
  const int wn = (w & 1) * 64;
  const int fr = lane & 15;
  const int fk = (lane >> 4) * 8;
  const half_t* pa = &As[(wm + fr) * 32 + fk];
  const half_t* pb = &Bs[(wn + fr) * 32 + fk];

  f32x4 acc[4][4] = {};

  for (int kt = 0; kt < KH; kt += 32) {
    __syncthreads();
    async_copy16(ga0 + kt, la0);
    async_copy16(ga1 + kt, la1);
    async_copy16(gb0 + kt, lb0);
    async_copy16(gb1 + kt, lb1);
    __syncthreads();

    f16x8 af[4], bf[4];
#pragma unroll
    for (int mi = 0; mi < 4; ++mi) af[mi] = *(const f16x8*)(pa + mi * 16 * 32);
#pragma unroll
    for (int ni = 0; ni < 4; ++ni) bf[ni] = *(const f16x8*)(pb + ni * 16 * 32);
#pragma unroll
    for (int mi = 0; mi < 4; ++mi)
#pragma unroll
      for (int ni = 0; ni < 4; ++ni)
        acc[mi][ni] = __builtin_amdgcn_mfma_f32_16x16x32_f16(
            af[mi], bf[ni], acc[mi][ni], 0, 0, 0);
  }

  float* Cp = blockIdx.z ? Cp1 : Cp0;
  const int er = (lane >> 4) * 4;
  const int ec = lane & 15;
#pragma unroll
  for (int mi = 0; mi < 4; ++mi) {
#pragma unroll
    for (int ni = 0; ni < 4; ++ni) {
      long gn = col0 + wn + ni * 16 + ec;
#pragma unroll
      for (int r = 0; r < 4; ++r) {
        long gm = row0 + wm + mi * 16 + er + r;
        Cp[gm * N + gn] = acc[mi][ni][r];
      }
    }
  }
}

// ---------------- split-K reduce: qkvc = f16(C0 + C1 + bias) ---------------
// grid (N/4/256, M) = (3, 2048); one float4 per thread; partials are L3-hot.
__global__ __launch_bounds__(256) void splitk_reduce_kernel(
    const float4* __restrict__ C0, const float4* __restrict__ C1,
    const float4* __restrict__ bias4, f16x4* __restrict__ dst)
{
  const int col  = blockIdx.x * 256 + threadIdx.x;   // 0..767 (N/4)
  const long row = blockIdx.y;                       // 0..2047
  const long i   = row * (CQKV / 4) + col;
  float4 a = C0[i];
  float4 b = C1[i];
  float4 bv = bias4[col];
  f16x4 h;
  h.x = (_Float16)(a.x + b.x + bv.x);
  h.y = (_Float16)(a.y + b.y + bv.y);
  h.z = (_Float16)(a.z + b.z + bv.z);
  h.w = (_Float16)(a.w + b.w + bv.w);
  dst[i] = h;
}

// ---------------- MFMA flash attention (compact 32-dim heads) --------------
// Block: 256 thr = 4 waves; wave w owns 16 queries [t0+16w, t0+16w+15].
// Two q-tiles per block {15-bx, bx} -> 17 chunks/block, perfectly balanced.
// Per 64-key chunk: S = Q.K^T (4 MFMA), P = exp2(S) masked -> LDS,
// O^T = Vt.P^T (6 MFMA; Vt row 32 = ones gives l in tile2 row 0).
#define VTS 72
#define PSS 72
__global__ __launch_bounds__(256, 4) void attn_kernel(
    const half_t* __restrict__ qkv,  // [MROWS][3072]
    half_t* __restrict__ attc)       // [MROWS][1024]
{
  __shared__ alignas(16) half_t Ks[64 * 32];        // [key][32]
  __shared__ alignas(16) half_t Vt[48 * VTS];       // [d][key], row 32 = ones
  __shared__ alignas(16) half_t Ps[4][16 * PSS];    // per-wave [q][key]

  const int tid  = threadIdx.x;
  const int lane = tid & 63;
  const int w    = tid >> 6;
  const int low  = lane & 15;
  const int quad = lane >> 4;
  const int bh   = blockIdx.y;
  const int b    = bh >> 5;
  const int h    = bh & 31;
  const long rb  = (long)b * TT;

  // ones row (d=32) of Vt, staged once (never overwritten)
  if (tid < 8) {
    f16x8 one;
#pragma unroll
    for (int i = 0; i < 8; ++i) one[i] = (_Float16)1.0f;
    *(f16x8*)&Vt[32 * VTS + tid * 8] = one;
  }

  const int srow = tid >> 2;            // 0..63
  const int sc4  = (tid & 3) << 3;      // 0,8,16,24
  half_t* ksdst  = &Ks[w * 512];        // wave-uniform; HW adds lane*16B
  half_t* psw    = &Ps[w][0];
  float*  Ob     = (float*)psw;         // epilogue overlay [q][36 floats]

  for (int pass = 0; pass < 2; ++pass) {
    const int tile = pass ? (int)blockIdx.x : 15 - (int)blockIdx.x;
    const int t0   = tile * 64;
    const int qg   = t0 + 16 * w;

    // Q fragment: A[m=low][k=quad*8+j]
    f16x8 qf = *(const f16x8*)&qkv[(rb + qg + low) * CQKV + h * 32 + quad * 8];

    f32x4 acc0 = {}, acc1 = {}, acc2 = {};
    const f32x4 zero = {};

    for (int c = 0; c <= t0; c += 64) {
      __syncthreads();
      // stage K (async direct-to-LDS) and V (register transpose scatter)
      const half_t* kg = &qkv[(rb + c + srow) * CQKV + 1024 + h * 32 + sc4];
      async_copy16(kg, ksdst);
      f16x8 vv = *(const f16x8*)(kg + 1024);
#pragma unroll
      for (int j = 0; j < 8; ++j)
        Vt[(sc4 + j) * VTS + srow] = vv[j];
      __syncthreads();

      // S = Q.K^T : C[m=q][n=key]
      f32x4 s[4];
#pragma unroll
      for (int st = 0; st < 4; ++st) {
        f16x8 kf = *(const f16x8*)&Ks[(st * 16 + low) * 32 + quad * 8];
        s[st] = __builtin_amdgcn_mfma_f32_16x16x32_f16(qf, kf, zero, 0, 0, 0);
      }

      // P = exp2(S) (causal mask only at diagonal chunk), write to LDS
      const bool diag = (c == t0);
#pragma unroll
      for (int st = 0; st < 4; ++st) {
#pragma unroll
        for (int r = 0; r < 4; ++r) {
          const int key = c + st * 16 + low;
          const int q   = qg + 4 * quad + r;
          float p = __builtin_amdgcn_exp2f(s[st][r]);
          if (diag && key > q) p = 0.f;
          psw[(4 * quad + r) * PSS + st * 16 + low] = (_Float16)p;
        }
      }

      // P frags (B: [n=q][k=key]) and Vt frags (A: [m=d][k=key])
      f16x8 p0 = *(const f16x8*)&psw[low * PSS + 0 * 32 + quad * 8];
      f16x8 p1 = *(const f16x8*)&psw[low * PSS + 1 * 32 + quad * 8];

      f16x8 v00 = *(const f16x8*)&Vt[(0  + low) * VTS + 0  + quad * 8];
      f16x8 v01 = *(const f16x8*)&Vt[(0  + low) * VTS + 32 + quad * 8];
      f16x8 v10 = *(const f16x8*)&Vt[(16 + low) * VTS + 0  + quad * 8];
      f16x8 v11 = *(const f16x8*)&Vt[(16 + low) * VTS + 32 + quad * 8];
      f16x8 v20 = *(const f16x8*)&Vt[(32 + low) * VTS + 0  + quad * 8];
      f16x8 v21 = *(const f16x8*)&Vt[(32 + low) * VTS + 32 + quad * 8];

      acc0 = __builtin_amdgcn_mfma_f32_16x16x32_f16(v00, p0, acc0, 0, 0, 0);
      acc0 = __builtin_amdgcn_mfma_f32_16x16x32_f16(v01, p1, acc0, 0, 0, 0);
      acc1 = __builtin_amdgcn_mfma_f32_16x16x32_f16(v10, p0, acc1, 0, 0, 0);
      acc1 = __builtin_amdgcn_mfma_f32_16x16x32_f16(v11, p1, acc1, 0, 0, 0);
      acc2 = __builtin_amdgcn_mfma_f32_16x16x32_f16(v20, p0, acc2, 0, 0, 0);
      acc2 = __builtin_amdgcn_mfma_f32_16x16x32_f16(v21, p1, acc2, 0, 0, 0);
    }

    // ---- epilogue ----
    __syncthreads();   // last chunk's Ps reads done before Ob overlay writes

    // l[q] lives in acc2[0] of lanes 0..15 (m=0 <=> d=32); broadcast by q
    float linv = 1.0f / __shfl(acc2[0], low);

    // O^T[d=16t+4quad+r][q=low] -> Ob[q][d], scaled
#pragma unroll
    for (int r = 0; r < 4; ++r) {
      Ob[low * 36 + 0  + 4 * quad + r] = acc0[r] * linv;
      Ob[low * 36 + 16 + 4 * quad + r] = acc1[r] * linv;
    }
    __syncthreads();

    // row-wise readback: lane (q=low, dblk=quad) -> 8 contiguous dims
    f16x8 ov;
#pragma unroll
    for (int i = 0; i < 8; ++i)
      ov[i] = (_Float16)Ob[low * 36 + quad * 8 + i];
    *(f16x8*)&attc[(rb + qg + low) * 1024 + h * 32 + quad * 8] = ov;
  }
}

// ---------------- launcher ----------------
extern "C" void kernel_launch(void* const* d_in, const int* in_sizes, int n_in,
                              void* d_out, int out_size, void* d_ws, size_t ws_size,
                              hipStream_t stream) {
  (void)in_sizes; (void)n_in; (void)out_size; (void)ws_size;
  const float* x  = (const float*)d_in[0];
  const float* W1 = (const float*)d_in[1];
  const float* b1 = (const float*)d_in[2];
  const float* W2 = (const float*)d_in[3];
  const float* b2 = (const float*)d_in[4];
  float* out = (float*)d_out;

  const size_t nX   = (size_t)MROWS * DIMX;   //  8,388,608
  const size_t nW1f = (size_t)CQKV  * DIMX;   // 12,582,912
  const size_t nW2f = (size_t)DIMX  * 1024;   //  4,194,304
  const size_t nQKV = (size_t)MROWS * CQKV;   //  6,291,456
  const size_t nATT = (size_t)MROWS * 1024;   //  2,097,152

  half_t* ws   = (half_t*)d_ws;
  half_t* xh   = ws;
  half_t* w1f  = xh   + nX;
  half_t* w2f  = w1f  + nW1f;
  half_t* qkvc = w2f  + nW2f;
  half_t* attc = qkvc + nQKV;
  float*  b1f  = (float*)(attc + nATT);       // 3072 floats
  // split-K partials: C0 reuses d_out (2048*4096 f32 >= 2048*3072 f32,
  // fully overwritten by GEMM2 at the end); C1 in workspace tail.
  float*  c1   = (float*)(b1f + 4096);        // 16B-aligned; 25.2 MB

  cvt_f32_f16_kernel<<<4096, 256, 0, stream>>>((const float4*)x, (f16x4*)xh,
                                               (int)(nX / 4));
  fold_w1_kernel<<<12288, 256, 0, stream>>>(W1, b1, w1f, b1f);
  fold_w2_kernel<<<4096, 256, 0, stream>>>(W2, w2f);

  // GEMM1: split-K=2 -> 768 blocks (3/CU) of 128x128x2048 partials
  gemm_nt_splitk<<<dim3(CQKV / 128, MROWS / 128, 2), 256, 0, stream>>>(
      xh, w1f, out /*C0*/, c1 /*C1*/, MROWS, CQKV, DIMX);
  splitk_reduce_kernel<<<dim3(CQKV / 4 / 256, MROWS), 256, 0, stream>>>(
      (const float4*)out, (const float4*)c1, (const float4*)b1f,
      (f16x4*)qkvc);

  attn_kernel<<<dim3(8, BB * NH), 256, 0, stream>>>(qkvc, attc);

  gemm_nt_bias<0><<<dim3(DIMX / 128, MROWS / 128), 256, 0, stream>>>(
      attc, w2f, b2, (void*)out, MROWS, DIMX, 1024);
}

// Round 3
// 343.965 us; speedup vs baseline: 1.0924x; 1.0694x over previous
//
#include <hip/hip_runtime.h>

// ---------------- problem constants ----------------
#define DIMX  4096
#define NH    32
#define HD    128
#define BB    2
#define TT    1024
#define MROWS (BB*TT)          // 2048
#define CQKV  3072             // compact qkv cols: 1024 q_red | 1024 k | 1024 v
// (1/sqrt(128)) * log2(e): lets attention use exp2 directly
#define SCALE_Q 0.12751743f

typedef _Float16 half_t;
typedef __attribute__((ext_vector_type(4))) _Float16 f16x4;
typedef __attribute__((ext_vector_type(8))) _Float16 f16x8;
typedef __attribute__((ext_vector_type(4))) float    f32x4;

// async global->LDS, 16B/lane; LDS dest = wave-uniform base + lane*16
__device__ __forceinline__ void async_copy16(const void* gsrc, void* ldst) {
  __builtin_amdgcn_global_load_lds(
      (const __attribute__((address_space(1))) unsigned int*)gsrc,
      (__attribute__((address_space(3))) unsigned int*)ldst,
      16, 0, 0);
}

// ---------------- fp32 -> fp16 conversion ----------------
__global__ __launch_bounds__(256) void cvt_f32_f16_kernel(
    const float4* __restrict__ src, f16x4* __restrict__ dst, int n4) {
  int stride = gridDim.x * blockDim.x;
  for (int i = blockIdx.x * blockDim.x + threadIdx.x; i < n4; i += stride) {
    float4 f = src[i];
    f16x4 h;
    h.x = (_Float16)f.x; h.y = (_Float16)f.y;
    h.z = (_Float16)f.z; h.w = (_Float16)f.w;
    dst[i] = h;
  }
}

// ---------------- fold W1 -> W1f [3072][4096] fp16, b1f [3072] f32 ----------
// rows 0..1023:  q_red rows = (sum of 4 q rows) * SCALE_Q
// rows 1024..3071: k/v rows copied (W1 row = row + 3072)
__global__ __launch_bounds__(256) void fold_w1_kernel(
    const float* __restrict__ W1, const float* __restrict__ b1,
    half_t* __restrict__ W1f, float* __restrict__ b1f)
{
  long idx = (long)blockIdx.x * 256 + threadIdx.x;   // 3072*1024
  int row = (int)(idx >> 10);
  int c4  = ((int)idx & 1023) << 2;
  f16x4 h;
  if (row < 1024) {
    const float* s = W1 + ((long)row << 2) * DIMX + c4;
    float4 a = *(const float4*)s;
    float4 b = *(const float4*)(s + DIMX);
    float4 c = *(const float4*)(s + 2 * DIMX);
    float4 d = *(const float4*)(s + 3 * DIMX);
    h.x = (_Float16)((a.x + b.x + c.x + d.x) * SCALE_Q);
    h.y = (_Float16)((a.y + b.y + c.y + d.y) * SCALE_Q);
    h.z = (_Float16)((a.z + b.z + c.z + d.z) * SCALE_Q);
    h.w = (_Float16)((a.w + b.w + c.w + d.w) * SCALE_Q);
    if (c4 == 0) {
      const float* bb = b1 + ((long)row << 2);
      b1f[row] = (bb[0] + bb[1] + bb[2] + bb[3]) * SCALE_Q;
    }
  } else {
    const float* s = W1 + ((long)(row + 3072)) * DIMX + c4;
    float4 a = *(const float4*)s;
    h.x = (_Float16)a.x; h.y = (_Float16)a.y;
    h.z = (_Float16)a.z; h.w = (_Float16)a.w;
    if (c4 == 0) b1f[row] = b1[row + 3072];
  }
  *(f16x4*)&W1f[(long)row * DIMX + c4] = h;
}

// ---------------- fold W2 -> W2f [4096][1024] fp16 ----------------
// W2f[n][j] = sum_{r<4} W2[n][4j+r]
__global__ __launch_bounds__(256) void fold_w2_kernel(
    const float* __restrict__ W2, half_t* __restrict__ W2f)
{
  long idx = (long)blockIdx.x * 256 + threadIdx.x;   // 4096*256
  int row = (int)(idx >> 8);
  int j4  = ((int)idx & 255) << 2;
  const float* s = W2 + (long)row * DIMX + ((long)j4 << 2);
  float4 a = *(const float4*)s;
  float4 b = *(const float4*)(s + 4);
  float4 c = *(const float4*)(s + 8);
  float4 d = *(const float4*)(s + 12);
  f16x4 h;
  h.x = (_Float16)(a.x + a.y + a.z + a.w);
  h.y = (_Float16)(b.x + b.y + b.z + b.w);
  h.z = (_Float16)(c.x + c.y + c.z + c.w);
  h.w = (_Float16)(d.x + d.y + d.z + d.w);
  *(f16x4*)&W2f[(long)row * 1024 + j4] = h;
}

// ============================================================================
// NT GEMM core, BK=64 + XOR chunk swizzle (T2, both-sides: rule #21).
// Tile 128x128, 4 waves 2x2, each wave 64x64 = 4x4 mfma_16x16x32 per kk.
// Rows in LDS are 128B = 8 chunks of 16B; stored chunk c holds global chunk
// (c ^ (row&7)).  Staging: per-lane GLOBAL source pre-swizzled, LDS dest
// linear (global_load_lds requirement).  Fragment reads XOR the same
// involution -> 2-way bank aliasing (free, m136) instead of 16-way.
// BK=64 halves barrier pairs / staging drains vs BK=32.
// ============================================================================

// ---------------- split-K NT GEMM (GEMM1): 2 K-slices, f32 partials --------
// grid (N/128, M/128, 2) = 768 blocks = 3/CU.
__global__ __launch_bounds__(256, 3) void gemm_nt_splitk(
    const half_t* __restrict__ A, const half_t* __restrict__ Bw,
    float* __restrict__ Cp0, float* __restrict__ Cp1,
    int M, int N, int K)
{
  __shared__ alignas(16) half_t As[128 * 64];   // 16 KB
  __shared__ alignas(16) half_t Bs[128 * 64];   // 16 KB

  const int tid  = threadIdx.x;
  const int lane = tid & 63;
  const int w    = tid >> 6;
  const long row0 = (long)blockIdx.y * 128;
  const long col0 = (long)blockIdx.x * 128;
  const int  KH   = K >> 1;
  const long k0   = (long)blockIdx.z * KH;

  // staging: thread t -> rows {i*32 + (t>>3)}, source chunk (t&7)^(row&7)
  const int rr = tid >> 3;                       // 0..31
  const int cs = (((tid & 7) ^ (rr & 7)) << 3);  // swizzled col (halves)
  const half_t* ga[4]; const half_t* gb[4];
#pragma unroll
  for (int i = 0; i < 4; ++i) {
    ga[i] = A  + (row0 + i * 32 + rr) * K + k0 + cs;
    gb[i] = Bw + (col0 + i * 32 + rr) * K + k0 + cs;
  }
  half_t* lds_a = &As[w * 512];   // + i*2048; HW adds lane*16B (linear) ✓
  half_t* lds_b = &Bs[w * 512];

  // wave 2x2: wave w owns C[wm..wm+63][wn..wn+63]
  const int wm = (w >> 1) * 64;
  const int wn = (w & 1) * 64;
  const int fr   = lane & 15;
  const int quad = lane >> 4;
  const int rsw  = fr & 7;
  const int o0 = ((quad ^ rsw) << 3);            // kk=0  chunk (halves)
  const int o1 = (((quad | 4) ^ rsw) << 3);      // kk=32 chunk
  const half_t* paw = &As[(wm + fr) * 64];
  const half_t* pbw = &Bs[(wn + fr) * 64];

  f32x4 acc[4][4] = {};

  for (int kt = 0; kt < KH; kt += 64) {
    __syncthreads();
#pragma unroll
    for (int i = 0; i < 4; ++i) async_copy16(ga[i] + kt, lds_a + i * 2048);
#pragma unroll
    for (int i = 0; i < 4; ++i) async_copy16(gb[i] + kt, lds_b + i * 2048);
    __syncthreads();   // compiler drains vmcnt(0) before s_barrier

    f16x8 af[4], bf[4];
#pragma unroll
    for (int mi = 0; mi < 4; ++mi) af[mi] = *(const f16x8*)(paw + mi * 1024 + o0);
#pragma unroll
    for (int ni = 0; ni < 4; ++ni) bf[ni] = *(const f16x8*)(pbw + ni * 1024 + o0);
#pragma unroll
    for (int mi = 0; mi < 4; ++mi)
#pragma unroll
      for (int ni = 0; ni < 4; ++ni)
        acc[mi][ni] = __builtin_amdgcn_mfma_f32_16x16x32_f16(
            af[mi], bf[ni], acc[mi][ni], 0, 0, 0);

#pragma unroll
    for (int mi = 0; mi < 4; ++mi) af[mi] = *(const f16x8*)(paw + mi * 1024 + o1);
#pragma unroll
    for (int ni = 0; ni < 4; ++ni) bf[ni] = *(const f16x8*)(pbw + ni * 1024 + o1);
#pragma unroll
    for (int mi = 0; mi < 4; ++mi)
#pragma unroll
      for (int ni = 0; ni < 4; ++ni)
        acc[mi][ni] = __builtin_amdgcn_mfma_f32_16x16x32_f16(
            af[mi], bf[ni], acc[mi][ni], 0, 0, 0);
  }

  float* Cp = blockIdx.z ? Cp1 : Cp0;
  // C/D layout: col = lane&15, row = (lane>>4)*4 + r
  const int er = (lane >> 4) * 4;
  const int ec = lane & 15;
#pragma unroll
  for (int mi = 0; mi < 4; ++mi) {
#pragma unroll
    for (int ni = 0; ni < 4; ++ni) {
      long gn = col0 + wn + ni * 16 + ec;
#pragma unroll
      for (int r = 0; r < 4; ++r) {
        long gm = row0 + wm + mi * 16 + er + r;
        Cp[gm * N + gn] = acc[mi][ni][r];
      }
    }
  }
}

// ---------------- plain NT GEMM + bias (GEMM2) -----------------------------
// Same BK=64 swizzled body; grid (N/128, M/128) = 512 blocks (even 2/CU).
template<int OUT_IS_F16>
__global__ __launch_bounds__(256, 3) void gemm_nt_bias(
    const half_t* __restrict__ A, const half_t* __restrict__ Bw,
    const float* __restrict__ bias, void* __restrict__ Cout,
    int M, int N, int K)
{
  __shared__ alignas(16) half_t As[128 * 64];   // 16 KB
  __shared__ alignas(16) half_t Bs[128 * 64];   // 16 KB

  const int tid  = threadIdx.x;
  const int lane = tid & 63;
  const int w    = tid >> 6;
  const long row0 = (long)blockIdx.y * 128;
  const long col0 = (long)blockIdx.x * 128;

  const int rr = tid >> 3;
  const int cs = (((tid & 7) ^ (rr & 7)) << 3);
  const half_t* ga[4]; const half_t* gb[4];
#pragma unroll
  for (int i = 0; i < 4; ++i) {
    ga[i] = A  + (row0 + i * 32 + rr) * K + cs;
    gb[i] = Bw + (col0 + i * 32 + rr) * K + cs;
  }
  half_t* lds_a = &As[w * 512];
  half_t* lds_b = &Bs[w * 512];

  const int wm = (w >> 1) * 64;
  const int wn = (w & 1) * 64;
  const int fr   = lane & 15;
  const int quad = lane >> 4;
  const int rsw  = fr & 7;
  const int o0 = ((quad ^ rsw) << 3);
  const int o1 = (((quad | 4) ^ rsw) << 3);
  const half_t* paw = &As[(wm + fr) * 64];
  const half_t* pbw = &Bs[(wn + fr) * 64];

  f32x4 acc[4][4] = {};

  for (int kt = 0; kt < K; kt += 64) {
    __syncthreads();
#pragma unroll
    for (int i = 0; i < 4; ++i) async_copy16(ga[i] + kt, lds_a + i * 2048);
#pragma unroll
    for (int i = 0; i < 4; ++i) async_copy16(gb[i] + kt, lds_b + i * 2048);
    __syncthreads();

    f16x8 af[4], bf[4];
#pragma unroll
    for (int mi = 0; mi < 4; ++mi) af[mi] = *(const f16x8*)(paw + mi * 1024 + o0);
#pragma unroll
    for (int ni = 0; ni < 4; ++ni) bf[ni] = *(const f16x8*)(pbw + ni * 1024 + o0);
#pragma unroll
    for (int mi = 0; mi < 4; ++mi)
#pragma unroll
      for (int ni = 0; ni < 4; ++ni)
        acc[mi][ni] = __builtin_amdgcn_mfma_f32_16x16x32_f16(
            af[mi], bf[ni], acc[mi][ni], 0, 0, 0);

#pragma unroll
    for (int mi = 0; mi < 4; ++mi) af[mi] = *(const f16x8*)(paw + mi * 1024 + o1);
#pragma unroll
    for (int ni = 0; ni < 4; ++ni) bf[ni] = *(const f16x8*)(pbw + ni * 1024 + o1);
#pragma unroll
    for (int mi = 0; mi < 4; ++mi)
#pragma unroll
      for (int ni = 0; ni < 4; ++ni)
        acc[mi][ni] = __builtin_amdgcn_mfma_f32_16x16x32_f16(
            af[mi], bf[ni], acc[mi][ni], 0, 0, 0);
  }

  const int er = (lane >> 4) * 4;
  const int ec = lane & 15;
#pragma unroll
  for (int mi = 0; mi < 4; ++mi) {
#pragma unroll
    for (int ni = 0; ni < 4; ++ni) {
      long gn = col0 + wn + ni * 16 + ec;
      float bv = bias[gn];
#pragma unroll
      for (int r = 0; r < 4; ++r) {
        long gm = row0 + wm + mi * 16 + er + r;
        float v = acc[mi][ni][r] + bv;
        if (OUT_IS_F16) ((half_t*)Cout)[gm * N + gn] = (half_t)v;
        else            ((float*)Cout)[gm * N + gn]  = v;
      }
    }
  }
}

// ---------------- split-K reduce: qkvc = f16(C0 + C1 + bias) ---------------
// grid (N/4/256, M) = (3, 2048); one float4 per thread; partials are L3-hot.
__global__ __launch_bounds__(256) void splitk_reduce_kernel(
    const float4* __restrict__ C0, const float4* __restrict__ C1,
    const float4* __restrict__ bias4, f16x4* __restrict__ dst)
{
  const int col  = blockIdx.x * 256 + threadIdx.x;   // 0..767 (N/4)
  const long row = blockIdx.y;                       // 0..2047
  const long i   = row * (CQKV / 4) + col;
  float4 a = C0[i];
  float4 b = C1[i];
  float4 bv = bias4[col];
  f16x4 h;
  h.x = (_Float16)(a.x + b.x + bv.x);
  h.y = (_Float16)(a.y + b.y + bv.y);
  h.z = (_Float16)(a.z + b.z + bv.z);
  h.w = (_Float16)(a.w + b.w + bv.w);
  dst[i] = h;
}

// ---------------- MFMA flash attention (compact 32-dim heads) --------------
// Block: 256 thr = 4 waves; wave w owns 16 queries [t0+16w, t0+16w+15].
// Grid (16, B*NH) = 1024 blocks (4/CU, was 2/CU with the 2-pass scheme);
// block bx owns q-tile bx with bx+1 key chunks; long blocks interleave
// every 16 in dispatch order so imbalance spreads across CUs.
// Per 64-key chunk: S = Q.K^T (4 MFMA), P = exp2(S) masked -> LDS,
// O^T = Vt.P^T (6 MFMA; Vt row 32 = ones gives l in tile2 row 0).
#define VTS 72
#define PSS 72
__global__ __launch_bounds__(256, 4) void attn_kernel(
    const half_t* __restrict__ qkv,  // [MROWS][3072]
    half_t* __restrict__ attc)       // [MROWS][1024]
{
  __shared__ alignas(16) half_t Ks[64 * 32];        // [key][32]
  __shared__ alignas(16) half_t Vt[48 * VTS];       // [d][key], row 32 = ones
  __shared__ alignas(16) half_t Ps[4][16 * PSS];    // per-wave [q][key]

  const int tid  = threadIdx.x;
  const int lane = tid & 63;
  const int w    = tid >> 6;
  const int low  = lane & 15;
  const int quad = lane >> 4;
  const int bh   = blockIdx.y;
  const int b    = bh >> 5;
  const int h    = bh & 31;
  const long rb  = (long)b * TT;

  // ones row (d=32) of Vt, staged once (never overwritten)
  if (tid < 8) {
    f16x8 one;
#pragma unroll
    for (int i = 0; i < 8; ++i) one[i] = (_Float16)1.0f;
    *(f16x8*)&Vt[32 * VTS + tid * 8] = one;
  }

  const int srow = tid >> 2;            // 0..63
  const int sc4  = (tid & 3) << 3;      // 0,8,16,24
  half_t* ksdst  = &Ks[w * 512];        // wave-uniform; HW adds lane*16B
  half_t* psw    = &Ps[w][0];
  float*  Ob     = (float*)psw;         // epilogue overlay [q][36 floats]

  const int tile = blockIdx.x;
  const int t0   = tile * 64;
  const int qg   = t0 + 16 * w;

  // Q fragment: A[m=low][k=quad*8+j]
  f16x8 qf = *(const f16x8*)&qkv[(rb + qg + low) * CQKV + h * 32 + quad * 8];

  f32x4 acc0 = {}, acc1 = {}, acc2 = {};
  const f32x4 zero = {};

  for (int c = 0; c <= t0; c += 64) {
    __syncthreads();
    // stage K (async direct-to-LDS) and V (register transpose scatter)
    const half_t* kg = &qkv[(rb + c + srow) * CQKV + 1024 + h * 32 + sc4];
    async_copy16(kg, ksdst);
    f16x8 vv = *(const f16x8*)(kg + 1024);
#pragma unroll
    for (int j = 0; j < 8; ++j)
      Vt[(sc4 + j) * VTS + srow] = vv[j];
    __syncthreads();

    // S = Q.K^T : C[m=q][n=key]
    f32x4 s[4];
#pragma unroll
    for (int st = 0; st < 4; ++st) {
      f16x8 kf = *(const f16x8*)&Ks[(st * 16 + low) * 32 + quad * 8];
      s[st] = __builtin_amdgcn_mfma_f32_16x16x32_f16(qf, kf, zero, 0, 0, 0);
    }

    // P = exp2(S) (causal mask only at diagonal chunk), write to LDS
    const bool diag = (c == t0);
#pragma unroll
    for (int st = 0; st < 4; ++st) {
#pragma unroll
      for (int r = 0; r < 4; ++r) {
        const int key = c + st * 16 + low;
        const int q   = qg + 4 * quad + r;
        float p = __builtin_amdgcn_exp2f(s[st][r]);
        if (diag && key > q) p = 0.f;
        psw[(4 * quad + r) * PSS + st * 16 + low] = (_Float16)p;
      }
    }

    // P frags (B: [n=q][k=key]) and Vt frags (A: [m=d][k=key])
    f16x8 p0 = *(const f16x8*)&psw[low * PSS + 0 * 32 + quad * 8];
    f16x8 p1 = *(const f16x8*)&psw[low * PSS + 1 * 32 + quad * 8];

    f16x8 v00 = *(const f16x8*)&Vt[(0  + low) * VTS + 0  + quad * 8];
    f16x8 v01 = *(const f16x8*)&Vt[(0  + low) * VTS + 32 + quad * 8];
    f16x8 v10 = *(const f16x8*)&Vt[(16 + low) * VTS + 0  + quad * 8];
    f16x8 v11 = *(const f16x8*)&Vt[(16 + low) * VTS + 32 + quad * 8];
    f16x8 v20 = *(const f16x8*)&Vt[(32 + low) * VTS + 0  + quad * 8];
    f16x8 v21 = *(const f16x8*)&Vt[(32 + low) * VTS + 32 + quad * 8];

    acc0 = __builtin_amdgcn_mfma_f32_16x16x32_f16(v00, p0, acc0, 0, 0, 0);
    acc0 = __builtin_amdgcn_mfma_f32_16x16x32_f16(v01, p1, acc0, 0, 0, 0);
    acc1 = __builtin_amdgcn_mfma_f32_16x16x32_f16(v10, p0, acc1, 0, 0, 0);
    acc1 = __builtin_amdgcn_mfma_f32_16x16x32_f16(v11, p1, acc1, 0, 0, 0);
    acc2 = __builtin_amdgcn_mfma_f32_16x16x32_f16(v20, p0, acc2, 0, 0, 0);
    acc2 = __builtin_amdgcn_mfma_f32_16x16x32_f16(v21, p1, acc2, 0, 0, 0);
  }

  // ---- epilogue ----
  __syncthreads();   // last chunk's Ps reads done before Ob overlay writes

  // l[q] lives in acc2[0] of lanes 0..15 (m=0 <=> d=32); broadcast by q
  float linv = 1.0f / __shfl(acc2[0], low);

  // O^T[d=16t+4quad+r][q=low] -> Ob[q][d], scaled
#pragma unroll
  for (int r = 0; r < 4; ++r) {
    Ob[low * 36 + 0  + 4 * quad + r] = acc0[r] * linv;
    Ob[low * 36 + 16 + 4 * quad + r] = acc1[r] * linv;
  }
  __syncthreads();

  // row-wise readback: lane (q=low, dblk=quad) -> 8 contiguous dims
  f16x8 ov;
#pragma unroll
  for (int i = 0; i < 8; ++i)
    ov[i] = (_Float16)Ob[low * 36 + quad * 8 + i];
  *(f16x8*)&attc[(rb + qg + low) * 1024 + h * 32 + quad * 8] = ov;
}

// ---------------- launcher ----------------
extern "C" void kernel_launch(void* const* d_in, const int* in_sizes, int n_in,
                              void* d_out, int out_size, void* d_ws, size_t ws_size,
                              hipStream_t stream) {
  (void)in_sizes; (void)n_in; (void)out_size; (void)ws_size;
  const float* x  = (const float*)d_in[0];
  const float* W1 = (const float*)d_in[1];
  const float* b1 = (const float*)d_in[2];
  const float* W2 = (const float*)d_in[3];
  const float* b2 = (const float*)d_in[4];
  float* out = (float*)d_out;

  const size_t nX   = (size_t)MROWS * DIMX;   //  8,388,608
  const size_t nW1f = (size_t)CQKV  * DIMX;   // 12,582,912
  const size_t nW2f = (size_t)DIMX  * 1024;   //  4,194,304
  const size_t nQKV = (size_t)MROWS * CQKV;   //  6,291,456
  const size_t nATT = (size_t)MROWS * 1024;   //  2,097,152

  half_t* ws   = (half_t*)d_ws;
  half_t* xh   = ws;
  half_t* w1f  = xh   + nX;
  half_t* w2f  = w1f  + nW1f;
  half_t* qkvc = w2f  + nW2f;
  half_t* attc = qkvc + nQKV;
  float*  b1f  = (float*)(attc + nATT);       // 3072 floats
  // split-K partials: C0 reuses d_out (2048*4096 f32 >= 2048*3072 f32,
  // fully overwritten by GEMM2 at the end); C1 in workspace tail.
  float*  c1   = (float*)(b1f + 4096);        // 16B-aligned; 25.2 MB

  cvt_f32_f16_kernel<<<4096, 256, 0, stream>>>((const float4*)x, (f16x4*)xh,
                                               (int)(nX / 4));
  fold_w1_kernel<<<12288, 256, 0, stream>>>(W1, b1, w1f, b1f);
  fold_w2_kernel<<<4096, 256, 0, stream>>>(W2, w2f);

  // GEMM1: split-K=2 -> 768 blocks (3/CU) of 128x128x2048 partials
  gemm_nt_splitk<<<dim3(CQKV / 128, MROWS / 128, 2), 256, 0, stream>>>(
      xh, w1f, out /*C0*/, c1 /*C1*/, MROWS, CQKV, DIMX);
  splitk_reduce_kernel<<<dim3(CQKV / 4 / 256, MROWS), 256, 0, stream>>>(
      (const float4*)out, (const float4*)c1, (const float4*)b1f,
      (f16x4*)qkvc);

  attn_kernel<<<dim3(16, BB * NH), 256, 0, stream>>>(qkvc, attc);

  gemm_nt_bias<0><<<dim3(DIMX / 128, MROWS / 128), 256, 0, stream>>>(
      attc, w2f, b2, (void*)out, MROWS, DIMX, 1024);
}